// Round 4
// baseline (3558.160 us; speedup 1.0000x reference)
//
#include <hip/hip_runtime.h>

// 5-layer stacked LSTM, T=512 B=256 IN=64 H=128. Storage fp32; internal bf16
// MFMA with fp32 accum (R3 passed at absmax 4.9e-4 with this arithmetic).
//
// R4: cross-layer software pipeline. One persistent kernel, 80 blocks =
// 5 layers x 16 batch-groups; block l*16+bg so all 5 stages of a bg share an
// XCD (blockIdx%8 heuristic). Layer l streams h_t to layer l+1 through a
// 64-slot bf16 ring in d_ws; per-(l,bg) progress flags use agent-scope
// release/acquire atomics (cross-XCD-correct per guide G16). Sync latency
// folds into constant pipeline lag; wall = ~516 steps instead of 2560.
// Fallback: R3's layer-sequential path if ws_size is too small.

typedef unsigned short ushort_t;
typedef __attribute__((ext_vector_type(8))) short short8;
typedef __attribute__((ext_vector_type(4))) float floatx4;

#define T_STEPS 512
#define BATCH   256
#define HID     128
#define NL      5
#define NBG     16
#define RING_R  64            // ring slots (power of 2)
#define FLAG_STRIDE 16        // ints; 64B per flag, no false sharing
#define RING_ELEMS ((size_t)RING_R * BATCH * HID)   // bf16 per layer ring
#define FLAG_BYTES (NL * NBG * FLAG_STRIDE * 4)
#define WS_NEED (8192 + 4 * RING_ELEMS * 2)

__device__ __forceinline__ ushort_t f2bf(float f) {
  unsigned int u = __float_as_uint(f);
  u += 0x7FFF + ((u >> 16) & 1);  // RNE; values here are finite
  return (ushort_t)(u >> 16);
}
__device__ __forceinline__ float sigm(float x) {
  float e = __builtin_amdgcn_exp2f(-1.442695041f * x);
  return __builtin_amdgcn_rcpf(1.0f + e);
}
__device__ __forceinline__ float tanh_(float x) {
  float e = __builtin_amdgcn_exp2f(-2.885390082f * x);
  float s = __builtin_amdgcn_rcpf(1.0f + e);
  return __builtin_fmaf(2.0f, s, -1.0f);
}

// ---------------------------------------------------------------- pipeline --
template <int KIN, bool SRC_F32>
__device__ __forceinline__ void lstm_stage(
    const float* xf32,              // layer 0 input (fp32) if SRC_F32
    const ushort_t* xbf,            // upstream ring (bf16) otherwise
    const float* __restrict__ Wih, const float* __restrict__ Whh,
    const float* __restrict__ bih, const float* __restrict__ bhh,
    ushort_t* ring_out,             // this layer's ring (null for last layer)
    float* out_f32,                 // d_out (last layer only)
    int* up_flag, int* down_flag, int* my_flag, int bg)
{
  constexpr int KX = KIN / 32, KT = KX + 4;
  const int tid  = threadIdx.x;
  const int wave = tid >> 6;
  const int lane = tid & 63;
  const int col  = lane & 15;        // MFMA: A row / D col
  const int quad = lane >> 4;        // MFMA: k-group / D row-group
  const int j    = wave * 16 + col;  // gate/h column owned by this lane

  __shared__ ushort_t Ah[2][16][136];  // own-h exchange, double buffered
  for (int i = tid; i < 2 * 16 * 136; i += 512) (&Ah[0][0][0])[i] = 0;

  // Wcat^T fragments, fp32 -> bf16 once, VGPR-resident all 512 steps.
  short8 wf[4][KT];
#pragma unroll
  for (int nt = 0; nt < 4; ++nt) {
    int n = nt * 128 + j;
#pragma unroll
    for (int kt = 0; kt < KX; ++kt) {
      const float* p = Wih + n * KIN + kt * 32 + quad * 8;
      short8 w;
#pragma unroll
      for (int e = 0; e < 8; ++e) w[e] = (short)f2bf(p[e]);
      wf[nt][kt] = w;
    }
#pragma unroll
    for (int kt = 0; kt < 4; ++kt) {
      const float* p = Whh + n * 128 + kt * 32 + quad * 8;
      short8 w;
#pragma unroll
      for (int e = 0; e < 8; ++e) w[e] = (short)f2bf(p[e]);
      wf[nt][KX + kt] = w;
    }
  }
  const float bi  = bih[j]       + bhh[j];
  const float bf_ = bih[128 + j] + bhh[128 + j];
  const float bgi = bih[256 + j] + bhh[256 + j];
  const float bo  = bih[384 + j] + bhh[384 + j];

  floatx4 c = {0.f, 0.f, 0.f, 0.f};
  int down_seen = 0;
  __syncthreads();

  for (int t = 0; t < T_STEPS; ++t) {
    // wait for upstream h_t (consumers only)
    if (!SRC_F32) {
      while (__hip_atomic_load(up_flag, __ATOMIC_RELAXED,
                               __HIP_MEMORY_SCOPE_AGENT) < t + 1)
        __builtin_amdgcn_s_sleep(2);
    }
    // ring-reuse guard: slot t%R is free once downstream finished step t-R
    if (ring_out) {
      while (t - down_seen >= RING_R)
        down_seen = __hip_atomic_load(down_flag, __ATOMIC_RELAXED,
                                      __HIP_MEMORY_SCOPE_AGENT);
    }
    __builtin_amdgcn_fence(__ATOMIC_ACQUIRE, "agent");

    // A-fragments: [x_t ; h_{t-1}], A[m=col][k=quad*8+i] per 32-wide k-tile
    short8 af[KT];
    if (SRC_F32) {
      const float* p = xf32 + ((size_t)t * BATCH + bg * 16 + col) * KIN + quad * 8;
#pragma unroll
      for (int kt = 0; kt < KX; ++kt) {
        short8 a;
#pragma unroll
        for (int e = 0; e < 8; ++e) a[e] = (short)f2bf(p[kt * 32 + e]);
        af[kt] = a;
      }
    } else {
      const ushort_t* p = xbf +
          ((size_t)(t & (RING_R - 1)) * BATCH + bg * 16 + col) * HID + quad * 8;
#pragma unroll
      for (int kt = 0; kt < KX; ++kt)
        af[kt] = *(const short8*)(p + kt * 32);
    }
#pragma unroll
    for (int kt = 0; kt < 4; ++kt)
      af[KX + kt] = *(const short8*)(&Ah[t & 1][col][kt * 32 + quad * 8]);

    floatx4 a0 = {0, 0, 0, 0}, a1 = {0, 0, 0, 0}, a2 = {0, 0, 0, 0},
            a3 = {0, 0, 0, 0};
#pragma unroll
    for (int kt = 0; kt < KT; ++kt) {
      short8 a = af[kt];
      a0 = __builtin_amdgcn_mfma_f32_16x16x32_bf16(a, wf[0][kt], a0, 0, 0, 0);
      a1 = __builtin_amdgcn_mfma_f32_16x16x32_bf16(a, wf[1][kt], a1, 0, 0, 0);
      a2 = __builtin_amdgcn_mfma_f32_16x16x32_bf16(a, wf[2][kt], a2, 0, 0, 0);
      a3 = __builtin_amdgcn_mfma_f32_16x16x32_bf16(a, wf[3][kt], a3, 0, 0, 0);
    }

    ushort_t (*wr)[136] = Ah[(t & 1) ^ 1];
    ushort_t* rbase = ring_out
        ? ring_out + ((size_t)(t & (RING_R - 1)) * BATCH + bg * 16) * HID + j
        : nullptr;
    float* obase = out_f32
        ? out_f32 + ((size_t)t * BATCH + bg * 16) * HID + j
        : nullptr;
#pragma unroll
    for (int r = 0; r < 4; ++r) {
      int row = quad * 4 + r;
      float iv = sigm(a0[r] + bi);
      float fv = sigm(a1[r] + bf_);
      float gv = tanh_(a2[r] + bgi);
      float ov = sigm(a3[r] + bo);
      float cn = __builtin_fmaf(fv, c[r], iv * gv);
      c[r] = cn;
      float hv = ov * tanh_(cn);
      ushort_t hb = f2bf(hv);
      wr[row][j] = hb;                        // own recurrence
      if (ring_out) rbase[(size_t)row * HID] = hb;   // downstream handoff
      else          obase[(size_t)row * HID] = hv;   // final fp32 output
    }
    __syncthreads();  // drains vmcnt (stores at L2) + orders LDS buffers
    if (tid == 0)     // publish step t done (release -> wbl2, cross-XCD safe)
      __hip_atomic_store(my_flag, t + 1, __ATOMIC_RELEASE,
                         __HIP_MEMORY_SCOPE_AGENT);
  }
}

__global__ void init_flags(int* flags) {
  int i = blockIdx.x * 256 + threadIdx.x;
  if (i < NL * NBG * FLAG_STRIDE) flags[i] = 0;
}

__global__ __launch_bounds__(512) void lstm_pipe(
    const float* x, const float* Wih0, const float* WihR,
    const float* Whh, const float* bih, const float* bhh,
    float* out, ushort_t* ring, int* flags)
{
  const int l  = blockIdx.x >> 4;   // blockIdx = l*16+bg -> bg%8 XCD affinity
  const int bg = blockIdx.x & 15;
  int* mine = flags + (l * NBG + bg) * FLAG_STRIDE;
  int* up   = (l > 0) ? flags + ((l - 1) * NBG + bg) * FLAG_STRIDE : nullptr;
  int* down = (l < 4) ? flags + ((l + 1) * NBG + bg) * FLAG_STRIDE : nullptr;

  if (l == 0) {
    lstm_stage<64, true>(x, nullptr, Wih0, Whh, bih, bhh,
                         ring, nullptr, up, down, mine, bg);
  } else if (l < 4) {
    lstm_stage<128, false>(nullptr, ring + (size_t)(l - 1) * RING_ELEMS,
                           WihR + (size_t)(l - 1) * 512 * 128,
                           Whh + (size_t)l * 512 * 128,
                           bih + l * 512, bhh + l * 512,
                           ring + (size_t)l * RING_ELEMS, nullptr,
                           up, down, mine, bg);
  } else {
    lstm_stage<128, false>(nullptr, ring + (size_t)3 * RING_ELEMS,
                           WihR + (size_t)3 * 512 * 128,
                           Whh + (size_t)4 * 512 * 128,
                           bih + 4 * 512, bhh + 4 * 512,
                           nullptr, out, up, nullptr, mine, bg);
  }
}

// ------------------------------------------------- fallback (R3, verified) --
template <int KIN>
__global__ __launch_bounds__(512) void lstm_layer(
    const float* xin, float* hout,
    const float* __restrict__ Wih, const float* __restrict__ Whh,
    const float* __restrict__ bih, const float* __restrict__ bhh)
{
  constexpr int KX = KIN / 32, KT = KX + 4;
  constexpr int AW = KIN + 128, AS = AW + 8;
  constexpr int NSTG = 16 * KIN / 4;

  const int bg = blockIdx.x, tid = threadIdx.x;
  const int wave = tid >> 6, lane = tid & 63;
  const int col = lane & 15, quad = lane >> 4;
  const int j = wave * 16 + col;

  __shared__ __align__(16) ushort_t Ah[2][16][AS];
  for (int i = tid; i < 2 * 16 * AS; i += 512) (&Ah[0][0][0])[i] = 0;

  short8 wf[4][KT];
#pragma unroll
  for (int nt = 0; nt < 4; ++nt) {
    int n = nt * 128 + j;
#pragma unroll
    for (int kt = 0; kt < KX; ++kt) {
      const float* p = Wih + n * KIN + kt * 32 + quad * 8;
      short8 w;
#pragma unroll
      for (int e = 0; e < 8; ++e) w[e] = (short)f2bf(p[e]);
      wf[nt][kt] = w;
    }
#pragma unroll
    for (int kt = 0; kt < 4; ++kt) {
      const float* p = Whh + n * 128 + kt * 32 + quad * 8;
      short8 w;
#pragma unroll
      for (int e = 0; e < 8; ++e) w[e] = (short)f2bf(p[e]);
      wf[nt][KX + kt] = w;
    }
  }
  const float bi  = bih[j]       + bhh[j];
  const float bf_ = bih[128 + j] + bhh[128 + j];
  const float bgi = bih[256 + j] + bhh[256 + j];
  const float bo  = bih[384 + j] + bhh[384 + j];

  floatx4 c = {0.f, 0.f, 0.f, 0.f};
  const int srow = tid / (KIN / 4), scol = (tid % (KIN / 4)) * 4;
  floatx4 xv = {0.f, 0.f, 0.f, 0.f};
  auto stage_load = [&](int t) {
    if (tid < NSTG && t < T_STEPS)
      xv = *(const floatx4*)(xin + (size_t)(t * BATCH + bg * 16 + srow) * KIN + scol);
  };
  auto stage_store = [&](int t, ushort_t (*buf)[AS]) {
    if (tid < NSTG && t < T_STEPS) {
#pragma unroll
      for (int e = 0; e < 4; ++e) buf[srow][scol + e] = f2bf(xv[e]);
    }
  };
  __syncthreads();
  stage_load(0); stage_store(0, Ah[0]); stage_load(1);
  __syncthreads();

  for (int t = 0; t < T_STEPS; ++t) {
    ushort_t (*rd)[AS] = Ah[t & 1];
    ushort_t (*wr)[AS] = Ah[(t & 1) ^ 1];
    short8 af[KT];
#pragma unroll
    for (int kt = 0; kt < KT; ++kt)
      af[kt] = *(const short8*)(&rd[col][kt * 32 + quad * 8]);
    floatx4 a0 = {0, 0, 0, 0}, a1 = {0, 0, 0, 0}, a2 = {0, 0, 0, 0},
            a3 = {0, 0, 0, 0};
#pragma unroll
    for (int kt = 0; kt < KT; ++kt) {
      short8 a = af[kt];
      a0 = __builtin_amdgcn_mfma_f32_16x16x32_bf16(a, wf[0][kt], a0, 0, 0, 0);
      a1 = __builtin_amdgcn_mfma_f32_16x16x32_bf16(a, wf[1][kt], a1, 0, 0, 0);
      a2 = __builtin_amdgcn_mfma_f32_16x16x32_bf16(a, wf[2][kt], a2, 0, 0, 0);
      a3 = __builtin_amdgcn_mfma_f32_16x16x32_bf16(a, wf[3][kt], a3, 0, 0, 0);
    }
    stage_store(t + 1, wr);
    stage_load(t + 2);
    size_t obase = (size_t)(t * BATCH + bg * 16) * HID + j;
#pragma unroll
    for (int r = 0; r < 4; ++r) {
      int row = quad * 4 + r;
      float iv = sigm(a0[r] + bi);
      float fv = sigm(a1[r] + bf_);
      float gv = tanh_(a2[r] + bgi);
      float ov = sigm(a3[r] + bo);
      float cn = __builtin_fmaf(fv, c[r], iv * gv);
      c[r] = cn;
      float hv = ov * tanh_(cn);
      wr[row][KIN + j] = f2bf(hv);
      hout[obase + (size_t)row * HID] = hv;
    }
    __syncthreads();
  }
}

extern "C" void kernel_launch(void* const* d_in, const int* in_sizes, int n_in,
                              void* d_out, int out_size, void* d_ws,
                              size_t ws_size, hipStream_t stream) {
  const float* x    = (const float*)d_in[0];  // [512,256,64]
  const float* Wih0 = (const float*)d_in[1];  // [512,64]
  const float* WihR = (const float*)d_in[2];  // [4,512,128]
  const float* Whh  = (const float*)d_in[3];  // [5,512,128]
  const float* bih  = (const float*)d_in[4];  // [5,512]
  const float* bhh  = (const float*)d_in[5];  // [5,512]
  float* out = (float*)d_out;                 // [512,256,128]

  if (ws_size >= WS_NEED) {
    int* flags = (int*)d_ws;
    ushort_t* ring = (ushort_t*)((char*)d_ws + 8192);
    init_flags<<<(NL * NBG * FLAG_STRIDE + 255) / 256, 256, 0, stream>>>(flags);
    lstm_pipe<<<NL * NBG, 512, 0, stream>>>(x, Wih0, WihR, Whh, bih, bhh,
                                            out, ring, flags);
  } else {
    lstm_layer<64><<<16, 512, 0, stream>>>(x, out, Wih0, Whh, bih, bhh);
    for (int l = 1; l < 5; ++l)
      lstm_layer<128><<<16, 512, 0, stream>>>(
          out, out, WihR + (size_t)(l - 1) * 512 * 128,
          Whh + (size_t)l * 512 * 128, bih + l * 512, bhh + l * 512);
  }
}

// Round 5
// 2569.596 us; speedup vs baseline: 1.3847x; 1.3847x over previous
//
#include <hip/hip_runtime.h>

// 5-layer stacked LSTM, T=512 B=256 IN=64 H=128. Storage fp32; internal bf16
// MFMA with fp32 accum (R3 verified, absmax 4.9e-4).
//
// R5: cross-layer pipeline (80 blocks = 5 layers x 16 batch-groups) with
// FENCE-FREE handoff. R4's regression (6.9us/step) was per-step bulk cache
// maintenance from agent fences / release stores (buffer_wbl2 + buffer_inv).
// R5 moves ALL cross-block traffic to relaxed agent-scope atomics (sc0/sc1
// point ops performed at L3, the device coherence point): h handoff packed to
// uint32 pairs via lane^1 shfl, flags relaxed. Producer order: ring stores ->
// __syncthreads (vmcnt drain) -> flag store. Consumer order: flag spin ->
// compiler barrier -> ring loads (issued first, h-MFMAs overlap the L3
// latency). Fallback: R3 layer-sequential path if ws too small.

typedef unsigned short ushort_t;
typedef unsigned int uint_t;
typedef __attribute__((ext_vector_type(8))) short short8;
typedef __attribute__((ext_vector_type(4))) float floatx4;

#define T_STEPS 512
#define BATCH   256
#define HID     128
#define NL      5
#define NBG     16
#define RING_R  64
#define FLAG_STRIDE 16
#define SLOT_U  (BATCH * HID / 2)                  // uints per ring slot
#define RING_U  ((size_t)RING_R * SLOT_U)          // uints per layer ring
#define WS_NEED (8192 + 4 * RING_U * 4)

__device__ __forceinline__ ushort_t f2bf(float f) {
  unsigned int u = __float_as_uint(f);
  u += 0x7FFF + ((u >> 16) & 1);  // RNE; values here are finite
  return (ushort_t)(u >> 16);
}
__device__ __forceinline__ float sigm(float x) {
  float e = __builtin_amdgcn_exp2f(-1.442695041f * x);
  return __builtin_amdgcn_rcpf(1.0f + e);
}
__device__ __forceinline__ float tanh_(float x) {
  float e = __builtin_amdgcn_exp2f(-2.885390082f * x);
  float s = __builtin_amdgcn_rcpf(1.0f + e);
  return __builtin_fmaf(2.0f, s, -1.0f);
}
__device__ __forceinline__ int flag_ld(const int* p) {
  return __hip_atomic_load(p, __ATOMIC_RELAXED, __HIP_MEMORY_SCOPE_AGENT);
}
__device__ __forceinline__ uint_t ring_ld(const uint_t* p) {
  return __hip_atomic_load(p, __ATOMIC_RELAXED, __HIP_MEMORY_SCOPE_AGENT);
}
__device__ __forceinline__ void ring_st(uint_t* p, uint_t v) {
  __hip_atomic_store(p, v, __ATOMIC_RELAXED, __HIP_MEMORY_SCOPE_AGENT);
}

__global__ void init_flags(int* flags) {
  int i = blockIdx.x * 256 + threadIdx.x;
  if (i < NL * NBG * FLAG_STRIDE)
    __hip_atomic_store(&flags[i], 0, __ATOMIC_RELAXED,
                       __HIP_MEMORY_SCOPE_AGENT);
}

// ---------------------------------------------------------------- pipeline --
template <int KIN, bool SRC_F32>
__device__ __forceinline__ void lstm_stage(
    const float* xf32,              // layer-0 input (fp32) if SRC_F32
    const uint_t* ring_in,          // upstream ring (packed bf16 pairs)
    const float* __restrict__ Wih, const float* __restrict__ Whh,
    const float* __restrict__ bih, const float* __restrict__ bhh,
    uint_t* ring_out,               // this layer's ring (null for last)
    float* out_f32,                 // d_out (last layer only)
    int* up_flag, int* down_flag, int* my_flag, int bg)
{
  constexpr int KX = KIN / 32, KT = KX + 4;
  const int tid  = threadIdx.x;
  const int wave = tid >> 6;
  const int lane = tid & 63;
  const int col  = lane & 15;        // MFMA: A row / D col
  const int quad = lane >> 4;        // MFMA: k-group / D row-group
  const int j    = wave * 16 + col;  // gate/h column owned by this lane

  __shared__ ushort_t Ah[2][16][136];  // own-h recurrence, double buffered
  for (int i = tid; i < 2 * 16 * 136; i += 512) (&Ah[0][0][0])[i] = 0;

  // Wcat^T fragments, fp32 -> bf16 once, VGPR-resident all 512 steps.
  short8 wf[4][KT];
#pragma unroll
  for (int nt = 0; nt < 4; ++nt) {
    int n = nt * 128 + j;
#pragma unroll
    for (int kt = 0; kt < KX; ++kt) {
      const float* p = Wih + n * KIN + kt * 32 + quad * 8;
      short8 w;
#pragma unroll
      for (int e = 0; e < 8; ++e) w[e] = (short)f2bf(p[e]);
      wf[nt][kt] = w;
    }
#pragma unroll
    for (int kt = 0; kt < 4; ++kt) {
      const float* p = Whh + n * 128 + kt * 32 + quad * 8;
      short8 w;
#pragma unroll
      for (int e = 0; e < 8; ++e) w[e] = (short)f2bf(p[e]);
      wf[nt][KX + kt] = w;
    }
  }
  const float bi  = bih[j]       + bhh[j];
  const float bf_ = bih[128 + j] + bhh[128 + j];
  const float bgi = bih[256 + j] + bhh[256 + j];
  const float bo  = bih[384 + j] + bhh[384 + j];

  floatx4 c = {0.f, 0.f, 0.f, 0.f};
  int down_seen = 0;

  // Stage-0 x prefetch registers (double-buffered, 16 fp32 each).
  floatx4 xr0[4], xr1[4];
  auto xload = [&](int t, floatx4* d) {
    if (SRC_F32 && t < T_STEPS) {
      const float* p = xf32 + ((size_t)t * BATCH + bg * 16 + col) * 64 + quad * 8;
      d[0] = *(const floatx4*)(p);
      d[1] = *(const floatx4*)(p + 4);
      d[2] = *(const floatx4*)(p + 32);
      d[3] = *(const floatx4*)(p + 36);
    }
  };
  if (SRC_F32) xload(0, xr0);
  __syncthreads();

  auto body = [&](int t, floatx4* xcur, floatx4* xnxt) {
    // ---- acquire upstream h_t ----
    uint_t xu[4][4];
    if (!SRC_F32) {
      while (flag_ld(up_flag) < t + 1) __builtin_amdgcn_s_sleep(1);
      asm volatile("" ::: "memory");  // no load hoisting above the spin
      const uint_t* p = ring_in + (size_t)(t & (RING_R - 1)) * SLOT_U +
                        (bg * 16 + col) * 64 + quad * 4;
#pragma unroll
      for (int kt = 0; kt < 4; ++kt)
#pragma unroll
        for (int e = 0; e < 4; ++e)
          xu[kt][e] = ring_ld(p + kt * 16 + e);
    } else {
      xload(t + 1, xnxt);  // issue next-step prefetch early
    }
    // ring-reuse guard: slot t%R free once downstream finished step t-R
    if (ring_out) {
      while (t - down_seen >= RING_R) {
        down_seen = flag_ld(down_flag);
        if (t - down_seen >= RING_R) __builtin_amdgcn_s_sleep(1);
      }
    }

    floatx4 a0 = {0, 0, 0, 0}, a1 = {0, 0, 0, 0}, a2 = {0, 0, 0, 0},
            a3 = {0, 0, 0, 0};
    // h-recurrence MFMAs first (LDS-fed; overlaps ring-load L3 latency)
#pragma unroll
    for (int kt = 0; kt < 4; ++kt) {
      short8 a = *(const short8*)(&Ah[t & 1][col][kt * 32 + quad * 8]);
      a0 = __builtin_amdgcn_mfma_f32_16x16x32_bf16(a, wf[0][KX + kt], a0, 0, 0, 0);
      a1 = __builtin_amdgcn_mfma_f32_16x16x32_bf16(a, wf[1][KX + kt], a1, 0, 0, 0);
      a2 = __builtin_amdgcn_mfma_f32_16x16x32_bf16(a, wf[2][KX + kt], a2, 0, 0, 0);
      a3 = __builtin_amdgcn_mfma_f32_16x16x32_bf16(a, wf[3][KX + kt], a3, 0, 0, 0);
    }
    // x MFMAs
#pragma unroll
    for (int kt = 0; kt < KX; ++kt) {
      short8 a;
      if (SRC_F32) {
#pragma unroll
        for (int e = 0; e < 4; ++e) {
          a[e]     = (short)f2bf(xcur[2 * kt][e]);
          a[4 + e] = (short)f2bf(xcur[2 * kt + 1][e]);
        }
      } else {
#pragma unroll
        for (int e = 0; e < 4; ++e) {
          a[2 * e]     = (short)(xu[kt][e] & 0xffff);
          a[2 * e + 1] = (short)(xu[kt][e] >> 16);
        }
      }
      a0 = __builtin_amdgcn_mfma_f32_16x16x32_bf16(a, wf[0][kt], a0, 0, 0, 0);
      a1 = __builtin_amdgcn_mfma_f32_16x16x32_bf16(a, wf[1][kt], a1, 0, 0, 0);
      a2 = __builtin_amdgcn_mfma_f32_16x16x32_bf16(a, wf[2][kt], a2, 0, 0, 0);
      a3 = __builtin_amdgcn_mfma_f32_16x16x32_bf16(a, wf[3][kt], a3, 0, 0, 0);
    }

    // ---- cell update (lane-local) ----
    ushort_t (*wr)[136] = Ah[(t & 1) ^ 1];
    ushort_t hb[4];
    float hv[4];
#pragma unroll
    for (int r = 0; r < 4; ++r) {
      float iv = sigm(a0[r] + bi);
      float fv = sigm(a1[r] + bf_);
      float gv = tanh_(a2[r] + bgi);
      float ov = sigm(a3[r] + bo);
      float cn = __builtin_fmaf(fv, c[r], iv * gv);
      c[r] = cn;
      hv[r] = ov * tanh_(cn);
      hb[r] = f2bf(hv[r]);
      wr[quad * 4 + r][j] = hb[r];  // own recurrence
    }

    if (ring_out) {
      // pack h-col pairs (j&~1, j|1) via lane^1 exchange -> 2 uint stores/lane
      uint_t other[4];
#pragma unroll
      for (int r = 0; r < 4; ++r)
        other[r] = (uint_t)__shfl_xor((int)hb[r], 1, 64) & 0xffff;
      uint_t* base = ring_out + (size_t)(t & (RING_R - 1)) * SLOT_U +
                     (bg * 16 + quad * 4) * 64 + (j >> 1);
      if ((j & 1) == 0) {
        ring_st(base + 0 * 64, (uint_t)hb[0] | (other[0] << 16));
        ring_st(base + 1 * 64, (uint_t)hb[1] | (other[1] << 16));
      } else {
        ring_st(base + 2 * 64, other[2] | ((uint_t)hb[2] << 16));
        ring_st(base + 3 * 64, other[3] | ((uint_t)hb[3] << 16));
      }
    } else {
      float* ob = out_f32 + ((size_t)t * BATCH + bg * 16 + quad * 4) * HID + j;
#pragma unroll
      for (int r = 0; r < 4; ++r) ob[(size_t)r * HID] = hv[r];
    }

    __syncthreads();  // drains vmcnt (ring stores done) + orders LDS buffers
    if (tid == 0)     // publish step t complete (point op at L3)
      __hip_atomic_store(my_flag, t + 1, __ATOMIC_RELAXED,
                         __HIP_MEMORY_SCOPE_AGENT);
  };

  for (int t = 0; t < T_STEPS; t += 2) {
    body(t,     xr0, xr1);
    body(t + 1, xr1, xr0);
  }
}

__global__ __launch_bounds__(512) void lstm_pipe(
    const float* x, const float* Wih0, const float* WihR,
    const float* Whh, const float* bih, const float* bhh,
    float* out, uint_t* ring, int* flags)
{
  const int l  = blockIdx.x >> 4;   // blockIdx = l*16+bg -> bg%8 XCD affinity
  const int bg = blockIdx.x & 15;
  int* mine = flags + (l * NBG + bg) * FLAG_STRIDE;
  int* up   = (l > 0) ? flags + ((l - 1) * NBG + bg) * FLAG_STRIDE : nullptr;
  int* down = (l < 4) ? flags + ((l + 1) * NBG + bg) * FLAG_STRIDE : nullptr;

  if (l == 0) {
    lstm_stage<64, true>(x, nullptr, Wih0, Whh, bih, bhh,
                         ring, nullptr, up, down, mine, bg);
  } else if (l < 4) {
    lstm_stage<128, false>(nullptr, ring + (size_t)(l - 1) * RING_U,
                           WihR + (size_t)(l - 1) * 512 * 128,
                           Whh + (size_t)l * 512 * 128,
                           bih + l * 512, bhh + l * 512,
                           ring + (size_t)l * RING_U, nullptr,
                           up, down, mine, bg);
  } else {
    lstm_stage<128, false>(nullptr, ring + (size_t)3 * RING_U,
                           WihR + (size_t)3 * 512 * 128,
                           Whh + (size_t)4 * 512 * 128,
                           bih + 4 * 512, bhh + 4 * 512,
                           nullptr, out, up, nullptr, mine, bg);
  }
}

// ------------------------------------------------- fallback (R3, verified) --
template <int KIN>
__global__ __launch_bounds__(512) void lstm_layer(
    const float* xin, float* hout,
    const float* __restrict__ Wih, const float* __restrict__ Whh,
    const float* __restrict__ bih, const float* __restrict__ bhh)
{
  constexpr int KX = KIN / 32, KT = KX + 4;
  constexpr int AW = KIN + 128, AS = AW + 8;
  constexpr int NSTG = 16 * KIN / 4;

  const int bg = blockIdx.x, tid = threadIdx.x;
  const int wave = tid >> 6, lane = tid & 63;
  const int col = lane & 15, quad = lane >> 4;
  const int j = wave * 16 + col;

  __shared__ __align__(16) ushort_t Ah[2][16][AS];
  for (int i = tid; i < 2 * 16 * AS; i += 512) (&Ah[0][0][0])[i] = 0;

  short8 wf[4][KT];
#pragma unroll
  for (int nt = 0; nt < 4; ++nt) {
    int n = nt * 128 + j;
#pragma unroll
    for (int kt = 0; kt < KX; ++kt) {
      const float* p = Wih + n * KIN + kt * 32 + quad * 8;
      short8 w;
#pragma unroll
      for (int e = 0; e < 8; ++e) w[e] = (short)f2bf(p[e]);
      wf[nt][kt] = w;
    }
#pragma unroll
    for (int kt = 0; kt < 4; ++kt) {
      const float* p = Whh + n * 128 + kt * 32 + quad * 8;
      short8 w;
#pragma unroll
      for (int e = 0; e < 8; ++e) w[e] = (short)f2bf(p[e]);
      wf[nt][KX + kt] = w;
    }
  }
  const float bi  = bih[j]       + bhh[j];
  const float bf_ = bih[128 + j] + bhh[128 + j];
  const float bgi = bih[256 + j] + bhh[256 + j];
  const float bo  = bih[384 + j] + bhh[384 + j];

  floatx4 c = {0.f, 0.f, 0.f, 0.f};
  const int srow = tid / (KIN / 4), scol = (tid % (KIN / 4)) * 4;
  floatx4 xv = {0.f, 0.f, 0.f, 0.f};
  auto stage_load = [&](int t) {
    if (tid < NSTG && t < T_STEPS)
      xv = *(const floatx4*)(xin + (size_t)(t * BATCH + bg * 16 + srow) * KIN + scol);
  };
  auto stage_store = [&](int t, ushort_t (*buf)[AS]) {
    if (tid < NSTG && t < T_STEPS) {
#pragma unroll
      for (int e = 0; e < 4; ++e) buf[srow][scol + e] = f2bf(xv[e]);
    }
  };
  __syncthreads();
  stage_load(0); stage_store(0, Ah[0]); stage_load(1);
  __syncthreads();

  for (int t = 0; t < T_STEPS; ++t) {
    ushort_t (*rd)[AS] = Ah[t & 1];
    ushort_t (*wr)[AS] = Ah[(t & 1) ^ 1];
    short8 af[KT];
#pragma unroll
    for (int kt = 0; kt < KT; ++kt)
      af[kt] = *(const short8*)(&rd[col][kt * 32 + quad * 8]);
    floatx4 a0 = {0, 0, 0, 0}, a1 = {0, 0, 0, 0}, a2 = {0, 0, 0, 0},
            a3 = {0, 0, 0, 0};
#pragma unroll
    for (int kt = 0; kt < KT; ++kt) {
      short8 a = af[kt];
      a0 = __builtin_amdgcn_mfma_f32_16x16x32_bf16(a, wf[0][kt], a0, 0, 0, 0);
      a1 = __builtin_amdgcn_mfma_f32_16x16x32_bf16(a, wf[1][kt], a1, 0, 0, 0);
      a2 = __builtin_amdgcn_mfma_f32_16x16x32_bf16(a, wf[2][kt], a2, 0, 0, 0);
      a3 = __builtin_amdgcn_mfma_f32_16x16x32_bf16(a, wf[3][kt], a3, 0, 0, 0);
    }
    stage_store(t + 1, wr);
    stage_load(t + 2);
    size_t obase = (size_t)(t * BATCH + bg * 16) * HID + j;
#pragma unroll
    for (int r = 0; r < 4; ++r) {
      int row = quad * 4 + r;
      float iv = sigm(a0[r] + bi);
      float fv = sigm(a1[r] + bf_);
      float gv = tanh_(a2[r] + bgi);
      float ov = sigm(a3[r] + bo);
      float cn = __builtin_fmaf(fv, c[r], iv * gv);
      c[r] = cn;
      float hv = ov * tanh_(cn);
      wr[row][KIN + j] = f2bf(hv);
      hout[obase + (size_t)row * HID] = hv;
    }
    __syncthreads();
  }
}

extern "C" void kernel_launch(void* const* d_in, const int* in_sizes, int n_in,
                              void* d_out, int out_size, void* d_ws,
                              size_t ws_size, hipStream_t stream) {
  const float* x    = (const float*)d_in[0];  // [512,256,64]
  const float* Wih0 = (const float*)d_in[1];  // [512,64]
  const float* WihR = (const float*)d_in[2];  // [4,512,128]
  const float* Whh  = (const float*)d_in[3];  // [5,512,128]
  const float* bih  = (const float*)d_in[4];  // [5,512]
  const float* bhh  = (const float*)d_in[5];  // [5,512]
  float* out = (float*)d_out;                 // [512,256,128]

  if (ws_size >= WS_NEED) {
    int* flags = (int*)d_ws;
    uint_t* ring = (uint_t*)((char*)d_ws + 8192);
    init_flags<<<(NL * NBG * FLAG_STRIDE + 255) / 256, 256, 0, stream>>>(flags);
    lstm_pipe<<<NL * NBG, 512, 0, stream>>>(x, Wih0, WihR, Whh, bih, bhh,
                                            out, ring, flags);
  } else {
    lstm_layer<64><<<16, 512, 0, stream>>>(x, out, Wih0, Whh, bih, bhh);
    for (int l = 1; l < 5; ++l)
      lstm_layer<128><<<16, 512, 0, stream>>>(
          out, out, WihR + (size_t)(l - 1) * 512 * 128,
          Whh + (size_t)l * 512 * 128, bih + l * 512, bhh + l * 512);
  }
}